// Round 16
// baseline (536.225 us; speedup 1.0000x reference)
//
#include <hip/hip_runtime.h>
#include <cstdint>
#include <cstddef>

#define N_BOX 5000
#define NW    80
#define LDX   1040
#define LDZ   2048
#define LDYM  1000
#define LDW   1040
#define LDAB  2080
#define NCHUNK ((N_BOX + 63) / 64)   // 79
#define RT    ((N_BOX + 255) / 256)  // 20

typedef short bf16x8 __attribute__((ext_vector_type(8)));
typedef float f32x4v __attribute__((ext_vector_type(4)));
typedef unsigned short u16x8 __attribute__((ext_vector_type(8)));

__device__ __forceinline__ float fence_f(float x) { asm volatile("" : "+v"(x)); return x; }

__device__ __forceinline__ unsigned short f2bf(float x) {
    unsigned u = __builtin_bit_cast(unsigned, x);
    unsigned r = (u + 0x7FFFu + ((u >> 16) & 1u)) >> 16;
    return (unsigned short)r;
}
__device__ __forceinline__ float bf2f(unsigned short h) {
    unsigned u = ((unsigned)h) << 16;
    return __builtin_bit_cast(float, u);
}

// ---------------- rank partial: tiled counting rank (400 blocks), atomicAdd ----------------
__global__ void rank_partial_kernel(const float* __restrict__ cls, int* __restrict__ rank) {
    __shared__ float sj[256];
    int t = threadIdx.x;
    int jbase = blockIdx.y * 256;
    int jg = jbase + t;
    sj[t] = (jg < N_BOX) ? cls[2 * jg + 1] : 0.0f;
    __syncthreads();
    int i = blockIdx.x * 256 + t;
    if (i >= N_BOX) return;
    float si = cls[2 * i + 1];
    int jmax = (N_BOX - jbase < 256) ? (N_BOX - jbase) : 256;
    int r = 0;
    for (int k = 0; k < jmax; ++k) {
        float sjv = sj[k];
        int j = jbase + k;
        r += (sjv > si) || (sjv == si && j < i);
    }
    atomicAdd(&rank[i], r);
}

__global__ void rank_scatter_kernel(const int* __restrict__ rank, int* __restrict__ ord) {
    int i = blockIdx.x * blockDim.x + threadIdx.x;
    if (i < N_BOX) ord[rank[i]] = i;
}

// ---------------- gather sorted boxes + build X0 + write L0 A2 bf16 [ah|al] directly ----------------
// grid 5120: rows >= N_BOX only zero the A2 pad row
__global__ void gather_kernel(const float* __restrict__ bb, const float* __restrict__ cls,
                              const float* __restrict__ feats, const float* __restrict__ img,
                              const int* __restrict__ ord,
                              float* __restrict__ X0, float* __restrict__ sb,
                              unsigned short* __restrict__ A2) {
    int r = blockIdx.x;
    if (r >= N_BOX) {
        unsigned short* dst = A2 + (size_t)r * LDAB;
        for (int k = threadIdx.x; k < 2048; k += blockDim.x) dst[k] = 0;
        return;
    }
    int i = ord[r];
    float x1 = bb[4 * i + 0], y1 = bb[4 * i + 1], x2 = bb[4 * i + 2], y2 = bb[4 * i + 3];
    float H = img[0], W = img[1];
    float sc = cls[2 * i + 1];
    if (threadIdx.x == 0) {
        sb[0 * N_BOX + r] = x1;
        sb[1 * N_BOX + r] = y1;
        sb[2 * N_BOX + r] = x2;
        sb[3 * N_BOX + r] = y2;
        sb[4 * N_BOX + r] = (x2 - x1 + 1.0f) * (y2 - y1 + 1.0f);
        sb[5 * N_BOX + r] = sc;
    }
    float width  = (x2 / W - x1 / W) / W;
    float height = (y2 / H - y1 / H) / H;
    float ar     = width / (height + 2.220446049250313e-16f);
    float areaf  = width * height;
    float* row = X0 + (size_t)r * LDX;
    unsigned short* a2row = A2 + (size_t)r * LDAB;
    for (int o = threadIdx.x; o < LDX; o += blockDim.x) {
        float v;
        if (o < 4)          v = (o == 0) ? x1 : (o == 1) ? y1 : (o == 2) ? x2 : y2;
        else if (o < 1028)  v = feats[(size_t)i * 1024 + (o - 4)];
        else if (o == 1028) v = width;
        else if (o == 1029) v = height;
        else if (o == 1030) v = ar;
        else if (o == 1031) v = areaf;
        else if (o == 1032) v = sc;
        else                v = 0.0f;
        row[o] = v;
        if (o >= 4 && o < 1028) {
            int k = o - 4;
            unsigned short hi = f2bf(v);
            a2row[k] = hi;
            a2row[1024 + k] = f2bf(v - bf2f(hi));
        }
    }
}

// ---------------- mask + inline diag + counts zero ----------------
__global__ void mask_kernel(const float* __restrict__ sb, unsigned long long* __restrict__ mask,
                            unsigned long long* __restrict__ diag, int* __restrict__ counts) {
    int j = blockIdx.x;
    if (threadIdx.x == 0) counts[j] = 0;
    const float* X1 = sb;
    const float* Y1 = sb + N_BOX;
    const float* X2 = sb + 2 * N_BOX;
    const float* Y2 = sb + 3 * N_BOX;
    const float* AR = sb + 4 * N_BOX;
    float xj1 = X1[j], yj1 = Y1[j], xj2 = X2[j], yj2 = Y2[j], aj = AR[j];
    int lane = threadIdx.x & 63;
    int wave = threadIdx.x >> 6;
    int nwav = blockDim.x >> 6;
    int dw = j >> 6;
    for (int w = wave; w < NW; w += nwav) {
        int i = w * 64 + lane;
        bool pred = false;
        if (i < N_BOX) {
            float iw = fmaxf(fminf(xj2, X2[i]) - fmaxf(xj1, X1[i]) + 1.0f, 0.0f);
            float ih = fmaxf(fminf(yj2, Y2[i]) - fmaxf(yj1, Y1[i]) + 1.0f, 0.0f);
            float ov = fence_f(iw * ih);
            float denom = fence_f((aj + AR[i]) - ov);
            pred = (ov / denom) > 0.5f;
        }
        unsigned long long b = __ballot(pred);
        if (lane == 0) {
            mask[(size_t)j * NW + w] = b;
            if (w == dw) diag[j] = b;
        }
    }
}

// ---------------- NMS body (r8 scheme) ----------------
__device__ __forceinline__ void nms_body(const unsigned long long* __restrict__ mask,
                                         const unsigned long long* __restrict__ diag,
                                         unsigned long long* __restrict__ keep,
                                         unsigned long long* supp,
                                         unsigned long long* keep_sh,
                                         unsigned long long* rem_sh,
                                         unsigned long long* kb_sh) {
    int tid = threadIdx.x;
    int l = tid & 63;
    int w = tid >> 6;
    if (tid < 80) supp[tid] = 0ULL;
    unsigned long long dg = 0ULL, dg_next = 0ULL;
    if (w == 0) dg = diag[l];
    __syncthreads();
    for (int c = 0; c < NCHUNK; ++c) {
        if (w == 0) {
            unsigned long long curv = supp[c];
            unsigned clo = __builtin_amdgcn_readfirstlane((unsigned)curv);
            unsigned chi = __builtin_amdgcn_readfirstlane((unsigned)(curv >> 32));
            unsigned long long cur = ((unsigned long long)chi << 32) | clo;
            int jmax = (N_BOX - c * 64 < 64) ? (N_BOX - c * 64) : 64;
            unsigned long long valid = (jmax >= 64) ? ~0ULL : ((1ULL << jmax) - 1ULL);
            unsigned long long rem = ~cur & valid;
            if (l == 0) *rem_sh = rem;
        }
        __syncthreads();
        unsigned long long rem0 = *rem_sh;
        unsigned long long a0 = 0, a1 = 0, a2 = 0, a3 = 0, a4 = 0;
        unsigned long long b0 = 0, b1 = 0, b2 = 0, b3 = 0, b4 = 0;
        unsigned mym = 0;
        int base = (w - 1) * 5;
        if (w > 0) {
            mym = (base < 64) ? (unsigned)((rem0 >> base) & 31ULL) : 0u;
            const unsigned long long* rowp = mask + (size_t)(c * 64 + base) * NW;
            if (mym & 1u)  { a0 = rowp[0 * NW + l]; b0 = (l < 16) ? rowp[0 * NW + 64 + l] : 0ULL; }
            if (mym & 2u)  { a1 = rowp[1 * NW + l]; b1 = (l < 16) ? rowp[1 * NW + 64 + l] : 0ULL; }
            if (mym & 4u)  { a2 = rowp[2 * NW + l]; b2 = (l < 16) ? rowp[2 * NW + 64 + l] : 0ULL; }
            if (mym & 8u)  { a3 = rowp[3 * NW + l]; b3 = (l < 16) ? rowp[3 * NW + 64 + l] : 0ULL; }
            if (mym & 16u) { a4 = rowp[4 * NW + l]; b4 = (l < 16) ? rowp[4 * NW + 64 + l] : 0ULL; }
            asm volatile("" : "+v"(a0), "+v"(a1), "+v"(a2), "+v"(a3), "+v"(a4),
                             "+v"(b0), "+v"(b1), "+v"(b2), "+v"(b3), "+v"(b4));
        } else {
            if (c + 1 < NCHUNK) dg_next = diag[(size_t)(c + 1) * 64 + l];
            unsigned rlo = __builtin_amdgcn_readfirstlane((unsigned)rem0);
            unsigned rhi = __builtin_amdgcn_readfirstlane((unsigned)(rem0 >> 32));
            unsigned long long remS = ((unsigned long long)rhi << 32) | rlo;
            unsigned long long kb = 0ULL;
            while (remS) {
                int jj = __builtin_ctzll(remS);
                kb |= 1ULL << jj;
                unsigned dlo = __builtin_amdgcn_readlane((unsigned)dg, jj);
                unsigned dhi = __builtin_amdgcn_readlane((unsigned)(dg >> 32), jj);
                unsigned long long dj = ((unsigned long long)dhi << 32) | dlo;
                remS &= ~dj;
                remS &= ~(1ULL << jj);
            }
            if (l == 0) { *kb_sh = kb; keep_sh[c] = kb; }
        }
        __syncthreads();
        if (w > 0 && mym) {
            unsigned long long kb = *kb_sh;
            unsigned kw = ((unsigned)((kb >> base) & 31ULL)) & mym;
            if (kw & 1u)  { atomicOr(&supp[l], a0); if (l < 16) atomicOr(&supp[64 + l], b0); }
            if (kw & 2u)  { atomicOr(&supp[l], a1); if (l < 16) atomicOr(&supp[64 + l], b1); }
            if (kw & 4u)  { atomicOr(&supp[l], a2); if (l < 16) atomicOr(&supp[64 + l], b2); }
            if (kw & 8u)  { atomicOr(&supp[l], a3); if (l < 16) atomicOr(&supp[64 + l], b3); }
            if (kw & 16u) { atomicOr(&supp[l], a4); if (l < 16) atomicOr(&supp[64 + l], b4); }
        }
        if (w == 0) dg = dg_next;
        __syncthreads();
    }
    if (tid < NCHUNK) keep[tid] = keep_sh[tid];
}

// ---------------- standalone NMS (fallback) ----------------
__global__ __launch_bounds__(1024) void nms_scan_kernel(const unsigned long long* __restrict__ mask,
                                                        const unsigned long long* __restrict__ diag,
                                                        unsigned long long* __restrict__ keep) {
    __shared__ unsigned long long supp[80];
    __shared__ unsigned long long keep_sh[NCHUNK];
    __shared__ unsigned long long rem_sh;
    __shared__ unsigned long long kb_sh;
    nms_body(mask, diag, keep, supp, keep_sh, &rem_sh, &kb_sh);
}

// ---------------- device helper: wconv rows, SINGLE-term bf16 ----------------
__device__ __forceinline__ void wconv_row(const float* __restrict__ Wg, const float* __restrict__ Wl,
                                          unsigned short* __restrict__ B2, int n, int tid2,
                                          int dout, int din, int K16) {
    unsigned short* dst = B2 + (size_t)n * LDAB;
    if (n >= 2 * dout) {
        for (int k = tid2; k < K16; k += 256) dst[k] = 0;
        return;
    }
    const float* src = (n < dout) ? (Wg + (size_t)n * din) : (Wl + (size_t)(n - dout) * din);
    for (int k = tid2; k < K16; k += 256) {
        float x = (k < din) ? src[k] : 0.0f;
        dst[k] = f2bf(x);
    }
}

// ---------------- FUSED: block0=NMS; 160 GEMM tiles; +e9 +w9 +wconv L1/2/3 roles ----------------
__global__ __launch_bounds__(1024) void nms_gemm_fused(const unsigned long long* __restrict__ mask,
                                                       const unsigned long long* __restrict__ diag,
                                                       unsigned long long* __restrict__ keep,
                                                       const unsigned short* __restrict__ A2,
                                                       const unsigned short* __restrict__ B2,
                                                       float* __restrict__ C, int KT, int Nn,
                                                       int MTiles,
                                                       const float* __restrict__ X0,
                                                       float* __restrict__ E9, float* __restrict__ W9,
                                                       const float* __restrict__ Wg1, const float* __restrict__ Wl1,
                                                       const float* __restrict__ Wg0full, const float* __restrict__ Wl0full,
                                                       unsigned short* __restrict__ B2_1,
                                                       const float* __restrict__ Wg2, const float* __restrict__ Wl2,
                                                       unsigned short* __restrict__ B2_2,
                                                       const float* __restrict__ Wg3, const float* __restrict__ Wl3,
                                                       unsigned short* __restrict__ B2_3) {
    __shared__ __align__(16) unsigned short AsBuf[2 * 8192];
    __shared__ __align__(16) unsigned short BsBuf[2 * 8192];
    int tid = threadIdx.x;
    int b = blockIdx.x;
    if (b == 0) {
        unsigned long long* supp    = (unsigned long long*)AsBuf;
        unsigned long long* keep_sh = supp + 80;
        unsigned long long* rem_sh  = keep_sh + NCHUNK;
        unsigned long long* kb_sh   = rem_sh + 1;
        nms_body(mask, diag, keep, supp, keep_sh, rem_sh, kb_sh);
        return;
    }
    int NG = MTiles * 8;
    if (b <= NG) {
        int t = b - 1;
        size_t bm = (size_t)(t % MTiles) * 256;
        size_t bn = (size_t)(t / MTiles) * 256;
        int lane = tid & 63;
        int wavef = tid >> 6;
        int wr = wavef >> 2, wc = wavef & 3;

        f32x4v acc[4][4];
#pragma unroll
        for (int i = 0; i < 4; ++i)
#pragma unroll
            for (int j = 0; j < 4; ++j) acc[i][j] = (f32x4v){0.f, 0.f, 0.f, 0.f};

        const unsigned short* gA = A2 + (bm + wavef * 16 + (lane & 15)) * (size_t)LDAB + (lane >> 4) * 8;
        const unsigned short* gB = B2 + (bn + wavef * 16 + (lane & 15)) * (size_t)LDAB + (lane >> 4) * 8;
        unsigned ldsoff = (unsigned)((wavef * 64 + lane) * 16);

#define FSTAGE(T, BUF)                                                                             \
        {                                                                                          \
            size_t ko = (size_t)(T) * 32;                                                          \
            __builtin_amdgcn_global_load_lds(                                                      \
                (const __attribute__((address_space(1))) void*)(gA + ko),                          \
                (__attribute__((address_space(3))) void*)((char*)AsBuf + (BUF) * 16384 + ldsoff),  \
                16, 0, 0);                                                                         \
            __builtin_amdgcn_global_load_lds(                                                      \
                (const __attribute__((address_space(1))) void*)(gB + ko),                          \
                (__attribute__((address_space(3))) void*)((char*)BsBuf + (BUF) * 16384 + ldsoff),  \
                16, 0, 0);                                                                         \
        }

        FSTAGE(0, 0);
        for (int kt = 0; kt < KT; ++kt) {
            int cur = kt & 1;
            if (kt + 1 < KT) {
                FSTAGE(kt + 1, cur ^ 1);
                asm volatile("s_waitcnt vmcnt(2)" ::: "memory");
            } else {
                asm volatile("s_waitcnt vmcnt(0)" ::: "memory");
            }
            asm volatile("s_barrier" ::: "memory");
            bf16x8 af[4], bf[4];
#pragma unroll
            for (int f4 = 0; f4 < 4; ++f4) {
                af[f4] = *(const bf16x8*)((const char*)AsBuf + cur * 16384 + ((wr * 4 + f4) * 64 + lane) * 16);
                bf[f4] = *(const bf16x8*)((const char*)BsBuf + cur * 16384 + ((wc * 4 + f4) * 64 + lane) * 16);
            }
#pragma unroll
            for (int i = 0; i < 4; ++i)
#pragma unroll
                for (int j = 0; j < 4; ++j)
                    acc[i][j] = __builtin_amdgcn_mfma_f32_16x16x32_bf16(af[i], bf[j], acc[i][j], 0, 0, 0);
            asm volatile("s_barrier" ::: "memory");
        }
#undef FSTAGE

#pragma unroll
        for (int i = 0; i < 4; ++i) {
            int r0 = (int)bm + wr * 64 + i * 16 + (lane >> 4) * 4;
#pragma unroll
            for (int j = 0; j < 4; ++j) {
                int col = (int)bn + wc * 64 + j * 16 + (lane & 15);
                if (col < Nn) {
#pragma unroll
                    for (int e = 0; e < 4; ++e) {
                        int r = r0 + e;
                        if (r < N_BOX) C[(size_t)r * LDZ + col] = acc[i][j][e];
                    }
                }
            }
        }
        return;
    }
    int rb = b - 1 - NG;
    const int cq[9] = {0, 1, 2, 3, 1028, 1029, 1030, 1031, 1032};
    if (rb < 5) {
        int r = rb * 1024 + tid;
        if (r < 5120) {
            float* dst = E9 + (size_t)r * 12;
#pragma unroll
            for (int q = 0; q < 9; ++q) dst[q] = (r < N_BOX) ? X0[(size_t)r * LDX + cq[q]] : 0.0f;
            dst[9] = dst[10] = dst[11] = 0.0f;
        }
        return;
    }
    rb -= 5;
    if (rb < 2) {
        int n = rb * 1024 + tid;
        if (n < 2048) {
            float* dst = W9 + (size_t)n * 12;
            const float* src = (n < 1000) ? (Wg0full + (size_t)n * 1033)
                             : (n < 2000) ? (Wl0full + (size_t)(n - 1000) * 1033) : nullptr;
#pragma unroll
            for (int q = 0; q < 9; ++q) dst[q] = src ? src[cq[q]] : 0.0f;
            dst[9] = dst[10] = dst[11] = 0.0f;
        }
        return;
    }
    rb -= 2;
    int rowl = tid >> 8;
    int tid2 = tid & 255;
    if (rb < 320) {
        int n = rb * 4 + rowl;
        if (n < 1280) wconv_row(Wg1, Wl1, B2_1, n, tid2, 600, 1000, 1024);
        return;
    }
    rb -= 320;
    if (rb < 160) {
        int n = rb * 4 + rowl;
        if (n < 640) wconv_row(Wg2, Wl2, B2_2, n, tid2, 300, 600, 608);
        return;
    }
    rb -= 160;
    {
        int n = rb * 4 + rowl;
        if (n < 384) wconv_row(Wg3, Wl3, B2_3, n, tid2, 150, 300, 320);
        return;
    }
}

// ---------------- z9 patch + assign fused ----------------
__global__ void z9_assign_kernel(float* __restrict__ Z, const float* __restrict__ E9,
                                 const float* __restrict__ W9, int Nn,
                                 const unsigned long long* __restrict__ mask,
                                 const unsigned long long* __restrict__ keep,
                                 int* __restrict__ assign, int* __restrict__ counts) {
    int b = blockIdx.x;
    if (b < N_BOX) {
        int r = b;
        float e[9];
#pragma unroll
        for (int q = 0; q < 9; ++q) e[q] = E9[(size_t)r * 12 + q];
        for (int o = threadIdx.x; o < Nn; o += blockDim.x) {
            const float* w = W9 + (size_t)o * 12;
            float s = 0.0f;
#pragma unroll
            for (int q = 0; q < 9; ++q) s += e[q] * w[q];
            Z[(size_t)r * LDZ + o] += s;
        }
        return;
    }
    int i = (b - N_BOX) * 256 + threadIdx.x;
    if (i >= N_BOX) return;
    for (int w = 0; w < NCHUNK; ++w) {
        unsigned long long m = mask[(size_t)i * NW + w] & keep[w];
        if (m) {
            int j = w * 64 + __builtin_ctzll(m);
            assign[i] = j;
            atomicAdd(&counts[j], 1);
            return;
        }
    }
}

// ---------------- assign (fallback) ----------------
__global__ void assign_kernel(const unsigned long long* __restrict__ mask,
                              const unsigned long long* __restrict__ keep,
                              int* __restrict__ assign, int* __restrict__ counts) {
    int i = blockIdx.x * blockDim.x + threadIdx.x;
    if (i >= N_BOX) return;
    for (int w = 0; w < NCHUNK; ++w) {
        unsigned long long m = mask[(size_t)i * NW + w] & keep[w];
        if (m) {
            int j = w * 64 + __builtin_ctzll(m);
            assign[i] = j;
            atomicAdd(&counts[j], 1);
            return;
        }
    }
}

// ---------------- exclusive scan ----------------
__global__ __launch_bounds__(1024) void scan_kernel(const int* __restrict__ counts, int* __restrict__ offs) {
    __shared__ int part[1024];
    int t = threadIdx.x;
    int base = t * 5;
    int c[5];
    int s = 0;
#pragma unroll
    for (int k = 0; k < 5; ++k) {
        int idx = base + k;
        c[k] = (idx < N_BOX) ? counts[idx] : 0;
        s += c[k];
    }
    part[t] = s;
    __syncthreads();
    for (int d = 1; d < 1024; d <<= 1) {
        int v = part[t];
        int u = (t >= d) ? part[t - d] : 0;
        __syncthreads();
        part[t] = v + u;
        __syncthreads();
    }
    int run = (t > 0) ? part[t - 1] : 0;
#pragma unroll
    for (int k = 0; k < 5; ++k) {
        int idx = base + k;
        if (idx < N_BOX) offs[idx] = run;
        run += c[k];
    }
}

// ---------------- deterministic member scatter ----------------
__global__ void rankscatter_kernel(const int* __restrict__ assign, const int* __restrict__ offs,
                                   int* __restrict__ members) {
    __shared__ int a[N_BOX];
    int tid = threadIdx.x;
    for (int t = tid; t < N_BOX; t += blockDim.x) a[t] = assign[t];
    __syncthreads();
    int i = blockIdx.x * blockDim.x + tid;
    if (i >= N_BOX) return;
    int ai = a[i];
    int r = 0;
    for (int k = 0; k < i; ++k) r += (a[k] == ai);
    members[offs[ai] + r] = i;
}

// ---------------- wconv standalone, 2-term (L0) ----------------
__global__ void wconv_kernel(const float* __restrict__ Wg, const float* __restrict__ Wl,
                             unsigned short* __restrict__ B2, int dout, int din_src,
                             int din_eff, int colOff, int K16eff) {
    int n = blockIdx.x;
    unsigned short* dst = B2 + (size_t)n * LDAB;
    int K2 = 2 * K16eff;
    if (n >= 2 * dout) {
        for (int k = threadIdx.x; k < K2; k += blockDim.x) dst[k] = 0;
        return;
    }
    const float* src = (n < dout) ? (Wg + (size_t)n * din_src) : (Wl + (size_t)(n - dout) * din_src);
    for (int k = threadIdx.x; k < K2; k += blockDim.x) {
        int ks = (k >= K16eff) ? (k - K16eff) : k;
        float x = (ks < din_eff) ? src[colOff + ks] : 0.0f;
        dst[k] = f2bf(x);
    }
}

// ---------------- MFMA bf16 GEMM, 128x128, BK=32, dbuf, 4 blk/CU (L1..L3) ----------------
__global__ __launch_bounds__(256, 4) void gemm_mfma(const unsigned short* __restrict__ A2,
                                                    const unsigned short* __restrict__ B2,
                                                    float* __restrict__ C, int KT, int Nn) {
    __shared__ unsigned short AsBuf[2 * 4096];
    __shared__ unsigned short BsBuf[2 * 4096];
    int tid = threadIdx.x;
    int lane = tid & 63;
    int wave = tid >> 6;
    int wr = wave >> 1, wc = wave & 1;
    size_t bm = (size_t)blockIdx.x * 128;
    size_t bn = (size_t)blockIdx.y * 128;

    f32x4v acc[4][4];
#pragma unroll
    for (int i = 0; i < 4; ++i)
#pragma unroll
        for (int j = 0; j < 4; ++j) acc[i][j] = (f32x4v){0.f, 0.f, 0.f, 0.f};

    const unsigned short* gA[2];
    const unsigned short* gB[2];
    unsigned ldsoff[2];
#pragma unroll
    for (int q = 0; q < 2; ++q) {
        int f = q * 4 + wave;
        int grow = f * 16 + (lane & 15);
        int gcol = (lane >> 4) * 8;
        gA[q] = A2 + (bm + grow) * (size_t)LDAB + gcol;
        gB[q] = B2 + (bn + grow) * (size_t)LDAB + gcol;
        ldsoff[q] = (unsigned)((f * 64 + lane) * 16);
    }

#define STAGE(T, BUF)                                                                              \
    {                                                                                              \
        size_t ko = (size_t)(T) * 32;                                                              \
        _Pragma("unroll") for (int q = 0; q < 2; ++q) {                                            \
            __builtin_amdgcn_global_load_lds(                                                      \
                (const __attribute__((address_space(1))) void*)(gA[q] + ko),                       \
                (__attribute__((address_space(3))) void*)((char*)AsBuf + (BUF) * 8192 + ldsoff[q]),\
                16, 0, 0);                                                                         \
            __builtin_amdgcn_global_load_lds(                                                      \
                (const __attribute__((address_space(1))) void*)(gB[q] + ko),                       \
                (__attribute__((address_space(3))) void*)((char*)BsBuf + (BUF) * 8192 + ldsoff[q]),\
                16, 0, 0);                                                                         \
        }                                                                                          \
    }

    STAGE(0, 0);
    for (int kt = 0; kt < KT; ++kt) {
        int cur = kt & 1;
        if (kt + 1 < KT) {
            STAGE(kt + 1, cur ^ 1);
            asm volatile("s_waitcnt vmcnt(4)" ::: "memory");
        } else {
            asm volatile("s_waitcnt vmcnt(0)" ::: "memory");
        }
        asm volatile("s_barrier" ::: "memory");
        bf16x8 af[4], bf[4];
#pragma unroll
        for (int f4 = 0; f4 < 4; ++f4) {
            af[f4] = *(const bf16x8*)((const char*)AsBuf + cur * 8192 + ((wr * 4 + f4) * 64 + lane) * 16);
            bf[f4] = *(const bf16x8*)((const char*)BsBuf + cur * 8192 + ((wc * 4 + f4) * 64 + lane) * 16);
        }
#pragma unroll
        for (int i = 0; i < 4; ++i)
#pragma unroll
            for (int j = 0; j < 4; ++j)
                acc[i][j] = __builtin_amdgcn_mfma_f32_16x16x32_bf16(af[i], bf[j], acc[i][j], 0, 0, 0);
        asm volatile("s_barrier" ::: "memory");
    }
#undef STAGE

#pragma unroll
    for (int i = 0; i < 4; ++i) {
        int r0 = (int)bm + wr * 64 + i * 16 + (lane >> 4) * 4;
#pragma unroll
        for (int j = 0; j < 4; ++j) {
            int col = (int)bn + wc * 64 + j * 16 + (lane & 15);
            if (col < Nn) {
#pragma unroll
                for (int e = 0; e < 4; ++e) {
                    int r = r0 + e;
                    if (r < N_BOX) C[(size_t)r * LDZ + col] = acc[i][j][e];
                }
            }
        }
    }
}

// ---------------- fused segmean+combine per cluster -> bf16 A2 single-term (L0..L2) ----------------
__global__ __launch_bounds__(256) void seg_combine_kernel(const float* __restrict__ Z,
                                                          const float* __restrict__ bg,
                                                          const int* __restrict__ counts,
                                                          const int* __restrict__ offs,
                                                          const int* __restrict__ members,
                                                          unsigned short* __restrict__ A2,
                                                          int dout, int K16next) {
    int j = blockIdx.x;
    int cnt = counts[j];
    if (cnt == 0) return;
    __shared__ float ymv[1024];
    int off = offs[j];
    float fc = (float)cnt;
    for (int o = threadIdx.x; o < dout; o += blockDim.x) {
        float s = 0.0f;
        for (int m = 0; m < cnt; ++m)
            s += Z[(size_t)members[off + m] * LDZ + dout + o];
        ymv[o] = s / fc;
    }
    __syncthreads();
    for (int m = 0; m < cnt; ++m) {
        int i = members[off + m];
        unsigned short* dst = A2 + (size_t)i * LDAB;
        const float* zr = Z + (size_t)i * LDZ;
        for (int o = threadIdx.x; o < K16next; o += blockDim.x) {
            float v = 0.0f;
            if (o < dout) {
                float z = zr[o] + bg[o] - ymv[o];
                v = (z > 0.0f) ? z : expm1f(z);
            }
            dst[o] = f2bf(v);
        }
    }
}

// ---------------- L3 segmean+combine + full L4 in one kernel ----------------
__global__ __launch_bounds__(256) void seg_l4_kernel(const float* __restrict__ Z,
                                                     const float* __restrict__ bg3,
                                                     const float* __restrict__ Wg4,
                                                     const float* __restrict__ bg4,
                                                     const float* __restrict__ Wl4,
                                                     const int* __restrict__ counts,
                                                     const int* __restrict__ offs,
                                                     const int* __restrict__ members,
                                                     float* __restrict__ out) {
    int j = blockIdx.x;
    int cnt = counts[j];
    if (cnt == 0) return;
    __shared__ float ymv[160];
    __shared__ float wsl[4];
    int off = offs[j];
    int tid = threadIdx.x;
    float fc = (float)cnt;
    // phase a: ym3 (identical member order as segmean)
    for (int o = tid; o < 150; o += 256) {
        float s = 0.0f;
        for (int m = 0; m < cnt; ++m)
            s += Z[(size_t)members[off + m] * LDZ + 150 + o];
        ymv[o] = s / fc;
    }
    __syncthreads();
    int l = tid & 63, w = tid >> 6;
    // phase b: ym4 = mean over members of dot(x, Wl4)
    float slsum = 0.0f;
    for (int m = w; m < cnt; m += 4) {
        int i = members[off + m];
        const float* zr = Z + (size_t)i * LDZ;
        float sl = 0.0f;
        for (int o = l; o < 150; o += 64) {
            float z = zr[o] + bg3[o] - ymv[o];
            float x = (z > 0.0f) ? z : expm1f(z);
            sl += x * Wl4[o];
        }
#pragma unroll
        for (int d = 1; d < 64; d <<= 1) sl += __shfl_xor(sl, d);
        slsum += sl;
    }
    if (l == 0) wsl[w] = slsum;
    __syncthreads();
    float ym4 = (wsl[0] + wsl[1] + wsl[2] + wsl[3]) / fc;
    // phase c: out[i] = cnt>=2 ? elu(dot(x,Wg4)+bg4-ym4) : 0
    for (int m = w; m < cnt; m += 4) {
        int i = members[off + m];
        const float* zr = Z + (size_t)i * LDZ;
        float sg = 0.0f;
        for (int o = l; o < 150; o += 64) {
            float z = zr[o] + bg3[o] - ymv[o];
            float x = (z > 0.0f) ? z : expm1f(z);
            sg += x * Wg4[o];
        }
#pragma unroll
        for (int d = 1; d < 64; d <<= 1) sg += __shfl_xor(sg, d);
        if (l == 0) {
            float z2 = sg + bg4[0] - ym4;
            float v = (z2 > 0.0f) ? z2 : expm1f(z2);
            out[i] = (cnt >= 2) ? v : 0.0f;
        }
    }
}

// ---------------- f32 fallback pack ----------------
__global__ void wcat_kernel(const float* __restrict__ Wg, const float* __restrict__ Wl,
                            float* __restrict__ Wc, int dout, int din, int K16) {
    int row = blockIdx.x;
    const float* src = (row < dout) ? (Wg + (size_t)row * din) : (Wl + (size_t)(row - dout) * din);
    float* dst = Wc + (size_t)row * LDW;
    for (int k = threadIdx.x; k < K16; k += blockDim.x)
        dst[k] = (k < din) ? src[k] : 0.0f;
}

// ---------------- f32 GEMM (fallback) ----------------
__global__ __launch_bounds__(256) void gemm_nt(const float* __restrict__ A, const float* __restrict__ B,
                                               float* __restrict__ C, int M, int Nn, int K16) {
    __shared__ float As[16][64];
    __shared__ float Bs[16][64];
    int bm = blockIdx.x * 64;
    int bn = blockIdx.y * 64;
    int tid = threadIdx.x;
    int row = tid & 63;
    int kq  = tid >> 6;
    int tx  = tid & 15;
    int ty  = tid >> 4;
    float acc[4][4] = {};
    for (int k0 = 0; k0 < K16; k0 += 16) {
        float4 av = make_float4(0.f, 0.f, 0.f, 0.f);
        float4 bv = make_float4(0.f, 0.f, 0.f, 0.f);
        if (bm + row < M)  av = *(const float4*)&A[(size_t)(bm + row) * LDX + k0 + kq * 4];
        if (bn + row < Nn) bv = *(const float4*)&B[(size_t)(bn + row) * LDW + k0 + kq * 4];
        __syncthreads();
        As[kq * 4 + 0][row] = av.x; As[kq * 4 + 1][row] = av.y;
        As[kq * 4 + 2][row] = av.z; As[kq * 4 + 3][row] = av.w;
        Bs[kq * 4 + 0][row] = bv.x; Bs[kq * 4 + 1][row] = bv.y;
        Bs[kq * 4 + 2][row] = bv.z; Bs[kq * 4 + 3][row] = bv.w;
        __syncthreads();
#pragma unroll
        for (int kk = 0; kk < 16; ++kk) {
            float4 a = *(const float4*)&As[kk][ty * 4];
            float4 b = *(const float4*)&Bs[kk][tx * 4];
            float aa[4] = {a.x, a.y, a.z, a.w};
            float bb[4] = {b.x, b.y, b.z, b.w};
#pragma unroll
            for (int i = 0; i < 4; ++i)
#pragma unroll
                for (int jx = 0; jx < 4; ++jx) acc[i][jx] += aa[i] * bb[jx];
        }
    }
#pragma unroll
    for (int i = 0; i < 4; ++i) {
        int r = bm + ty * 4 + i;
        if (r >= M) break;
#pragma unroll
        for (int jx = 0; jx < 4; ++jx) {
            int ccol = bn + tx * 4 + jx;
            if (ccol < Nn) C[(size_t)r * LDZ + ccol] = acc[i][jx];
        }
    }
}

// ---------------- segment mean of Zl (fallback) ----------------
__global__ void segmean_kernel(const float* __restrict__ Z, int dout,
                               const int* __restrict__ counts, const int* __restrict__ offs,
                               const int* __restrict__ members, float* __restrict__ ym) {
    int j = blockIdx.x;
    int cnt = counts[j];
    if (cnt == 0) return;
    int off = offs[j];
    float fc = (float)cnt;
    for (int o = threadIdx.x; o < dout; o += blockDim.x) {
        float s = 0.0f;
        for (int m = 0; m < cnt; ++m) {
            int i = members[off + m];
            s += Z[(size_t)i * LDZ + dout + o];
        }
        ym[(size_t)j * LDYM + o] = s / fc;
    }
}

// ---------------- combine + ELU -> f32 X (fallback) ----------------
__global__ void combine_kernel(const float* __restrict__ Z, const float* __restrict__ bg,
                               const float* __restrict__ ym, const int* __restrict__ assign,
                               float* __restrict__ Xout, int dout, int doutPad) {
    int r = blockIdx.x;
    int a = assign[r];
    float* dst = Xout + (size_t)r * LDX;
    for (int o = threadIdx.x; o < doutPad; o += blockDim.x) {
        float v = 0.0f;
        if (o < dout) {
            float z = Z[(size_t)r * LDZ + o] + bg[o] - ym[(size_t)a * LDYM + o];
            v = (z > 0.0f) ? z : expm1f(z);
        }
        dst[o] = v;
    }
}

// ---------------- final mask (fallback) ----------------
__global__ void final_kernel(const float* __restrict__ X, const int* __restrict__ assign,
                             const int* __restrict__ counts, float* __restrict__ out) {
    int r = blockIdx.x * blockDim.x + threadIdx.x;
    if (r >= N_BOX) return;
    out[r] = (counts[assign[r]] >= 2) ? X[(size_t)r * LDX] : 0.0f;
}

extern "C" void kernel_launch(void* const* d_in, const int* in_sizes, int n_in,
                              void* d_out, int out_size, void* d_ws, size_t ws_size,
                              hipStream_t stream) {
    const float* bb    = (const float*)d_in[0];
    const float* cls   = (const float*)d_in[1];
    const float* feats = (const float*)d_in[2];
    const float* img   = (const float*)d_in[3];

    char* ws = (char*)d_ws;
    size_t off = 0;
    auto alloc = [&](size_t bytes) -> void* {
        void* p = ws + off;
        off += (bytes + 255) & ~(size_t)255;
        return p;
    };
    int*   ord     = (int*)alloc((size_t)N_BOX * 4);
    int*   rankb   = (int*)alloc((size_t)N_BOX * 4);
    float* sb      = (float*)alloc((size_t)6 * N_BOX * 4);
    int*   assign  = (int*)alloc((size_t)N_BOX * 4);
    int*   counts  = (int*)alloc((size_t)N_BOX * 4);
    int*   offsb   = (int*)alloc((size_t)N_BOX * 4);
    int*   members = (int*)alloc((size_t)N_BOX * 4);
    unsigned long long* mask = (unsigned long long*)alloc((size_t)(NCHUNK * 64) * NW * 8);
    unsigned long long* diag = (unsigned long long*)alloc((size_t)NCHUNK * 64 * 8);
    unsigned long long* keep = (unsigned long long*)alloc((size_t)NCHUNK * 8 + 1024);
    float* Xa = (float*)alloc((size_t)N_BOX * LDX * 4);
    float* Xb = (float*)alloc((size_t)N_BOX * LDX * 4);
    float* Z  = (float*)alloc((size_t)N_BOX * LDZ * 4);
    float* ym = (float*)alloc((size_t)N_BOX * LDYM * 4);
    float* Wc = (float*)alloc((size_t)2000 * LDW * 4);
    unsigned short* A2   = (unsigned short*)alloc((size_t)5120 * LDAB * 2);
    unsigned short* B2_0 = (unsigned short*)alloc((size_t)2048 * LDAB * 2);
    unsigned short* B2_1 = (unsigned short*)alloc((size_t)1280 * LDAB * 2);
    unsigned short* B2_2 = (unsigned short*)alloc((size_t)640 * LDAB * 2);
    unsigned short* B2_3 = (unsigned short*)alloc((size_t)384 * LDAB * 2);
    float* E9 = (float*)alloc((size_t)5120 * 12 * 4);
    float* W9 = (float*)alloc((size_t)2048 * 12 * 4);
    bool use_mfma = (off <= ws_size);

    hipMemsetAsync(rankb, 0, (size_t)N_BOX * 4, stream);
    rank_partial_kernel<<<dim3(RT, RT), dim3(256), 0, stream>>>(cls, rankb);
    rank_scatter_kernel<<<dim3(RT), dim3(256), 0, stream>>>(rankb, ord);
    gather_kernel<<<dim3(5120), dim3(256), 0, stream>>>(bb, cls, feats, img, ord, Xa, sb, A2);
    mask_kernel<<<dim3(N_BOX), dim3(256), 0, stream>>>(sb, mask, diag, counts);

    const int dins[5]  = {1033, 1000, 600, 300, 150};
    const int douts[5] = {1000, 600, 300, 150, 1};
    const int K16s[4]  = {1024, 1024, 608, 320};   // L0: per-half (2-term); L1-3: single-term
    const int KTs[4]   = {64, 32, 19, 10};
    unsigned short* B2L[4] = {B2_0, B2_1, B2_2, B2_3};

    if (use_mfma) {
        wconv_kernel<<<dim3(2048), dim3(256), 0, stream>>>((const float*)d_in[4], (const float*)d_in[6],
                                                           B2_0, 1000, 1033, 1024, 4, 1024);
        nms_gemm_fused<<<dim3(744), dim3(1024), 0, stream>>>(
            mask, diag, keep, A2, B2_0, Z, KTs[0], 2000, 20,
            Xa, E9, W9,
            (const float*)d_in[7], (const float*)d_in[9],
            (const float*)d_in[4], (const float*)d_in[6],
            B2_1,
            (const float*)d_in[10], (const float*)d_in[12], B2_2,
            (const float*)d_in[13], (const float*)d_in[15], B2_3);
        z9_assign_kernel<<<dim3(N_BOX + RT), dim3(256), 0, stream>>>(Z, E9, W9, 2000,
                                                                     mask, keep, assign, counts);
        scan_kernel<<<dim3(1), dim3(1024), 0, stream>>>(counts, offsb);
        rankscatter_kernel<<<dim3(RT), dim3(256), 0, stream>>>(assign, offsb, members);

        // L0 tail + L1..L3
        seg_combine_kernel<<<dim3(N_BOX), dim3(256), 0, stream>>>(Z, (const float*)d_in[5],
                                                                  counts, offsb, members, A2, 1000, K16s[1]);
        gemm_mfma<<<dim3(40, 10), dim3(256), 0, stream>>>(A2, B2_1, Z, KTs[1], 1200);
        seg_combine_kernel<<<dim3(N_BOX), dim3(256), 0, stream>>>(Z, (const float*)d_in[8],
                                                                  counts, offsb, members, A2, 600, K16s[2]);
        gemm_mfma<<<dim3(40, 5), dim3(256), 0, stream>>>(A2, B2_2, Z, KTs[2], 600);
        seg_combine_kernel<<<dim3(N_BOX), dim3(256), 0, stream>>>(Z, (const float*)d_in[11],
                                                                  counts, offsb, members, A2, 300, K16s[3]);
        gemm_mfma<<<dim3(40, 3), dim3(256), 0, stream>>>(A2, B2_3, Z, KTs[3], 300);
        seg_l4_kernel<<<dim3(N_BOX), dim3(256), 0, stream>>>(Z, (const float*)d_in[14],
                                                             (const float*)d_in[16], (const float*)d_in[17],
                                                             (const float*)d_in[18],
                                                             counts, offsb, members, (float*)d_out);
    } else {
        nms_scan_kernel<<<dim3(1), dim3(1024), 0, stream>>>(mask, diag, keep);
        assign_kernel<<<dim3(RT), dim3(256), 0, stream>>>(mask, keep, assign, counts);
        scan_kernel<<<dim3(1), dim3(1024), 0, stream>>>(counts, offsb);
        rankscatter_kernel<<<dim3(RT), dim3(256), 0, stream>>>(assign, offsb, members);
        for (int L = 0; L < 5; ++L) {
            const float* Wg = (const float*)d_in[4 + 3 * L];
            const float* bg = (const float*)d_in[5 + 3 * L];
            const float* Wl = (const float*)d_in[6 + 3 * L];
            int din = dins[L], dout = douts[L];
            int K16 = (din + 15) & ~15;
            int N2 = 2 * dout;
            int doutPad = (dout + 15) & ~15;
            float* Xin  = (L % 2 == 0) ? Xa : Xb;
            float* Xout = (L % 2 == 0) ? Xb : Xa;
            wcat_kernel<<<dim3(N2), dim3(256), 0, stream>>>(Wg, Wl, Wc, dout, din, K16);
            gemm_nt<<<dim3((N_BOX + 63) / 64, (N2 + 63) / 64), dim3(256), 0, stream>>>(Xin, Wc, Z, N_BOX, N2, K16);
            segmean_kernel<<<dim3(N_BOX), dim3(256), 0, stream>>>(Z, dout, counts, offsb, members, ym);
            combine_kernel<<<dim3(N_BOX), dim3(256), 0, stream>>>(Z, bg, ym, assign, Xout, dout, doutPad);
        }
        final_kernel<<<dim3(RT), dim3(256), 0, stream>>>(Xb, assign, counts, (float*)d_out);
    }
}

// Round 17
// 467.180 us; speedup vs baseline: 1.1478x; 1.1478x over previous
//
#include <hip/hip_runtime.h>
#include <cstdint>
#include <cstddef>

#define N_BOX 5000
#define NW    80
#define LDX   1040
#define LDZ   2048
#define LDYM  1000
#define LDW   1040
#define LDAB  2080
#define NCHUNK ((N_BOX + 63) / 64)   // 79
#define RT    ((N_BOX + 255) / 256)  // 20

typedef short bf16x8 __attribute__((ext_vector_type(8)));
typedef float f32x4v __attribute__((ext_vector_type(4)));
typedef unsigned short u16x8 __attribute__((ext_vector_type(8)));

__device__ __forceinline__ float fence_f(float x) { asm volatile("" : "+v"(x)); return x; }

__device__ __forceinline__ unsigned short f2bf(float x) {
    unsigned u = __builtin_bit_cast(unsigned, x);
    unsigned r = (u + 0x7FFFu + ((u >> 16) & 1u)) >> 16;
    return (unsigned short)r;
}
__device__ __forceinline__ float bf2f(unsigned short h) {
    unsigned u = ((unsigned)h) << 16;
    return __builtin_bit_cast(float, u);
}

// ---------------- rank partial: tiled counting rank (400 blocks), atomicAdd ----------------
__global__ void rank_partial_kernel(const float* __restrict__ cls, int* __restrict__ rank) {
    __shared__ float sj[256];
    int t = threadIdx.x;
    int jbase = blockIdx.y * 256;
    int jg = jbase + t;
    sj[t] = (jg < N_BOX) ? cls[2 * jg + 1] : 0.0f;
    __syncthreads();
    int i = blockIdx.x * 256 + t;
    if (i >= N_BOX) return;
    float si = cls[2 * i + 1];
    int jmax = (N_BOX - jbase < 256) ? (N_BOX - jbase) : 256;
    int r = 0;
    for (int k = 0; k < jmax; ++k) {
        float sjv = sj[k];
        int j = jbase + k;
        r += (sjv > si) || (sjv == si && j < i);
    }
    atomicAdd(&rank[i], r);
}

__global__ void rank_scatter_kernel(const int* __restrict__ rank, int* __restrict__ ord) {
    int i = blockIdx.x * blockDim.x + threadIdx.x;
    if (i < N_BOX) ord[rank[i]] = i;
}

// ---------------- gather sorted boxes + build X0 + write L0 A2 bf16 [ah|al] directly ----------------
__global__ void gather_kernel(const float* __restrict__ bb, const float* __restrict__ cls,
                              const float* __restrict__ feats, const float* __restrict__ img,
                              const int* __restrict__ ord,
                              float* __restrict__ X0, float* __restrict__ sb,
                              unsigned short* __restrict__ A2) {
    int r = blockIdx.x;
    if (r >= N_BOX) {
        unsigned short* dst = A2 + (size_t)r * LDAB;
        for (int k = threadIdx.x; k < 2048; k += blockDim.x) dst[k] = 0;
        return;
    }
    int i = ord[r];
    float x1 = bb[4 * i + 0], y1 = bb[4 * i + 1], x2 = bb[4 * i + 2], y2 = bb[4 * i + 3];
    float H = img[0], W = img[1];
    float sc = cls[2 * i + 1];
    if (threadIdx.x == 0) {
        sb[0 * N_BOX + r] = x1;
        sb[1 * N_BOX + r] = y1;
        sb[2 * N_BOX + r] = x2;
        sb[3 * N_BOX + r] = y2;
        sb[4 * N_BOX + r] = (x2 - x1 + 1.0f) * (y2 - y1 + 1.0f);
        sb[5 * N_BOX + r] = sc;
    }
    float width  = (x2 / W - x1 / W) / W;
    float height = (y2 / H - y1 / H) / H;
    float ar     = width / (height + 2.220446049250313e-16f);
    float areaf  = width * height;
    float* row = X0 + (size_t)r * LDX;
    unsigned short* a2row = A2 + (size_t)r * LDAB;
    for (int o = threadIdx.x; o < LDX; o += blockDim.x) {
        float v;
        if (o < 4)          v = (o == 0) ? x1 : (o == 1) ? y1 : (o == 2) ? x2 : y2;
        else if (o < 1028)  v = feats[(size_t)i * 1024 + (o - 4)];
        else if (o == 1028) v = width;
        else if (o == 1029) v = height;
        else if (o == 1030) v = ar;
        else if (o == 1031) v = areaf;
        else if (o == 1032) v = sc;
        else                v = 0.0f;
        row[o] = v;
        if (o >= 4 && o < 1028) {
            int k = o - 4;
            unsigned short hi = f2bf(v);
            a2row[k] = hi;
            a2row[1024 + k] = f2bf(v - bf2f(hi));
        }
    }
}

// ---------------- mask + inline diag + counts zero ----------------
__global__ void mask_kernel(const float* __restrict__ sb, unsigned long long* __restrict__ mask,
                            unsigned long long* __restrict__ diag, int* __restrict__ counts) {
    int j = blockIdx.x;
    if (threadIdx.x == 0) counts[j] = 0;
    const float* X1 = sb;
    const float* Y1 = sb + N_BOX;
    const float* X2 = sb + 2 * N_BOX;
    const float* Y2 = sb + 3 * N_BOX;
    const float* AR = sb + 4 * N_BOX;
    float xj1 = X1[j], yj1 = Y1[j], xj2 = X2[j], yj2 = Y2[j], aj = AR[j];
    int lane = threadIdx.x & 63;
    int wave = threadIdx.x >> 6;
    int nwav = blockDim.x >> 6;
    int dw = j >> 6;
    for (int w = wave; w < NW; w += nwav) {
        int i = w * 64 + lane;
        bool pred = false;
        if (i < N_BOX) {
            float iw = fmaxf(fminf(xj2, X2[i]) - fmaxf(xj1, X1[i]) + 1.0f, 0.0f);
            float ih = fmaxf(fminf(yj2, Y2[i]) - fmaxf(yj1, Y1[i]) + 1.0f, 0.0f);
            float ov = fence_f(iw * ih);
            float denom = fence_f((aj + AR[i]) - ov);
            pred = (ov / denom) > 0.5f;
        }
        unsigned long long b = __ballot(pred);
        if (lane == 0) {
            mask[(size_t)j * NW + w] = b;
            if (w == dw) diag[j] = b;
        }
    }
}

// ---------------- NMS body (r8 scheme) ----------------
__device__ __forceinline__ void nms_body(const unsigned long long* __restrict__ mask,
                                         const unsigned long long* __restrict__ diag,
                                         unsigned long long* __restrict__ keep,
                                         unsigned long long* supp,
                                         unsigned long long* keep_sh,
                                         unsigned long long* rem_sh,
                                         unsigned long long* kb_sh) {
    int tid = threadIdx.x;
    int l = tid & 63;
    int w = tid >> 6;
    if (tid < 80) supp[tid] = 0ULL;
    unsigned long long dg = 0ULL, dg_next = 0ULL;
    if (w == 0) dg = diag[l];
    __syncthreads();
    for (int c = 0; c < NCHUNK; ++c) {
        if (w == 0) {
            unsigned long long curv = supp[c];
            unsigned clo = __builtin_amdgcn_readfirstlane((unsigned)curv);
            unsigned chi = __builtin_amdgcn_readfirstlane((unsigned)(curv >> 32));
            unsigned long long cur = ((unsigned long long)chi << 32) | clo;
            int jmax = (N_BOX - c * 64 < 64) ? (N_BOX - c * 64) : 64;
            unsigned long long valid = (jmax >= 64) ? ~0ULL : ((1ULL << jmax) - 1ULL);
            unsigned long long rem = ~cur & valid;
            if (l == 0) *rem_sh = rem;
        }
        __syncthreads();
        unsigned long long rem0 = *rem_sh;
        unsigned long long a0 = 0, a1 = 0, a2 = 0, a3 = 0, a4 = 0;
        unsigned long long b0 = 0, b1 = 0, b2 = 0, b3 = 0, b4 = 0;
        unsigned mym = 0;
        int base = (w - 1) * 5;
        if (w > 0) {
            mym = (base < 64) ? (unsigned)((rem0 >> base) & 31ULL) : 0u;
            const unsigned long long* rowp = mask + (size_t)(c * 64 + base) * NW;
            if (mym & 1u)  { a0 = rowp[0 * NW + l]; b0 = (l < 16) ? rowp[0 * NW + 64 + l] : 0ULL; }
            if (mym & 2u)  { a1 = rowp[1 * NW + l]; b1 = (l < 16) ? rowp[1 * NW + 64 + l] : 0ULL; }
            if (mym & 4u)  { a2 = rowp[2 * NW + l]; b2 = (l < 16) ? rowp[2 * NW + 64 + l] : 0ULL; }
            if (mym & 8u)  { a3 = rowp[3 * NW + l]; b3 = (l < 16) ? rowp[3 * NW + 64 + l] : 0ULL; }
            if (mym & 16u) { a4 = rowp[4 * NW + l]; b4 = (l < 16) ? rowp[4 * NW + 64 + l] : 0ULL; }
            asm volatile("" : "+v"(a0), "+v"(a1), "+v"(a2), "+v"(a3), "+v"(a4),
                             "+v"(b0), "+v"(b1), "+v"(b2), "+v"(b3), "+v"(b4));
        } else {
            if (c + 1 < NCHUNK) dg_next = diag[(size_t)(c + 1) * 64 + l];
            unsigned rlo = __builtin_amdgcn_readfirstlane((unsigned)rem0);
            unsigned rhi = __builtin_amdgcn_readfirstlane((unsigned)(rem0 >> 32));
            unsigned long long remS = ((unsigned long long)rhi << 32) | rlo;
            unsigned long long kb = 0ULL;
            while (remS) {
                int jj = __builtin_ctzll(remS);
                kb |= 1ULL << jj;
                unsigned dlo = __builtin_amdgcn_readlane((unsigned)dg, jj);
                unsigned dhi = __builtin_amdgcn_readlane((unsigned)(dg >> 32), jj);
                unsigned long long dj = ((unsigned long long)dhi << 32) | dlo;
                remS &= ~dj;
                remS &= ~(1ULL << jj);
            }
            if (l == 0) { *kb_sh = kb; keep_sh[c] = kb; }
        }
        __syncthreads();
        if (w > 0 && mym) {
            unsigned long long kb = *kb_sh;
            unsigned kw = ((unsigned)((kb >> base) & 31ULL)) & mym;
            if (kw & 1u)  { atomicOr(&supp[l], a0); if (l < 16) atomicOr(&supp[64 + l], b0); }
            if (kw & 2u)  { atomicOr(&supp[l], a1); if (l < 16) atomicOr(&supp[64 + l], b1); }
            if (kw & 4u)  { atomicOr(&supp[l], a2); if (l < 16) atomicOr(&supp[64 + l], b2); }
            if (kw & 8u)  { atomicOr(&supp[l], a3); if (l < 16) atomicOr(&supp[64 + l], b3); }
            if (kw & 16u) { atomicOr(&supp[l], a4); if (l < 16) atomicOr(&supp[64 + l], b4); }
        }
        if (w == 0) dg = dg_next;
        __syncthreads();
    }
    if (tid < NCHUNK) keep[tid] = keep_sh[tid];
}

// ---------------- standalone NMS (fallback) ----------------
__global__ __launch_bounds__(1024) void nms_scan_kernel(const unsigned long long* __restrict__ mask,
                                                        const unsigned long long* __restrict__ diag,
                                                        unsigned long long* __restrict__ keep) {
    __shared__ unsigned long long supp[80];
    __shared__ unsigned long long keep_sh[NCHUNK];
    __shared__ unsigned long long rem_sh;
    __shared__ unsigned long long kb_sh;
    nms_body(mask, diag, keep, supp, keep_sh, &rem_sh, &kb_sh);
}

// ---------------- device helper: wconv rows, SINGLE-term bf16 ----------------
__device__ __forceinline__ void wconv_row(const float* __restrict__ Wg, const float* __restrict__ Wl,
                                          unsigned short* __restrict__ B2, int n, int tid2,
                                          int dout, int din, int K16) {
    unsigned short* dst = B2 + (size_t)n * LDAB;
    if (n >= 2 * dout) {
        for (int k = tid2; k < K16; k += 256) dst[k] = 0;
        return;
    }
    const float* src = (n < dout) ? (Wg + (size_t)n * din) : (Wl + (size_t)(n - dout) * din);
    for (int k = tid2; k < K16; k += 256) {
        float x = (k < din) ? src[k] : 0.0f;
        dst[k] = f2bf(x);
    }
}

// ---------------- FUSED: block0=NMS; 160 GEMM tiles; +e9 +w9 +wconv L1/2/3 roles ----------------
__global__ __launch_bounds__(1024) void nms_gemm_fused(const unsigned long long* __restrict__ mask,
                                                       const unsigned long long* __restrict__ diag,
                                                       unsigned long long* __restrict__ keep,
                                                       const unsigned short* __restrict__ A2,
                                                       const unsigned short* __restrict__ B2,
                                                       float* __restrict__ C, int KT, int Nn,
                                                       int MTiles,
                                                       const float* __restrict__ X0,
                                                       float* __restrict__ E9, float* __restrict__ W9,
                                                       const float* __restrict__ Wg1, const float* __restrict__ Wl1,
                                                       const float* __restrict__ Wg0full, const float* __restrict__ Wl0full,
                                                       unsigned short* __restrict__ B2_1,
                                                       const float* __restrict__ Wg2, const float* __restrict__ Wl2,
                                                       unsigned short* __restrict__ B2_2,
                                                       const float* __restrict__ Wg3, const float* __restrict__ Wl3,
                                                       unsigned short* __restrict__ B2_3) {
    __shared__ __align__(16) unsigned short AsBuf[2 * 8192];
    __shared__ __align__(16) unsigned short BsBuf[2 * 8192];
    int tid = threadIdx.x;
    int b = blockIdx.x;
    if (b == 0) {
        unsigned long long* supp    = (unsigned long long*)AsBuf;
        unsigned long long* keep_sh = supp + 80;
        unsigned long long* rem_sh  = keep_sh + NCHUNK;
        unsigned long long* kb_sh   = rem_sh + 1;
        nms_body(mask, diag, keep, supp, keep_sh, rem_sh, kb_sh);
        return;
    }
    int NG = MTiles * 8;
    if (b <= NG) {
        int t = b - 1;
        size_t bm = (size_t)(t % MTiles) * 256;
        size_t bn = (size_t)(t / MTiles) * 256;
        int lane = tid & 63;
        int wavef = tid >> 6;
        int wr = wavef >> 2, wc = wavef & 3;

        f32x4v acc[4][4];
#pragma unroll
        for (int i = 0; i < 4; ++i)
#pragma unroll
            for (int j = 0; j < 4; ++j) acc[i][j] = (f32x4v){0.f, 0.f, 0.f, 0.f};

        const unsigned short* gA = A2 + (bm + wavef * 16 + (lane & 15)) * (size_t)LDAB + (lane >> 4) * 8;
        const unsigned short* gB = B2 + (bn + wavef * 16 + (lane & 15)) * (size_t)LDAB + (lane >> 4) * 8;
        unsigned ldsoff = (unsigned)((wavef * 64 + lane) * 16);

#define FSTAGE(T, BUF)                                                                             \
        {                                                                                          \
            size_t ko = (size_t)(T) * 32;                                                          \
            __builtin_amdgcn_global_load_lds(                                                      \
                (const __attribute__((address_space(1))) void*)(gA + ko),                          \
                (__attribute__((address_space(3))) void*)((char*)AsBuf + (BUF) * 16384 + ldsoff),  \
                16, 0, 0);                                                                         \
            __builtin_amdgcn_global_load_lds(                                                      \
                (const __attribute__((address_space(1))) void*)(gB + ko),                          \
                (__attribute__((address_space(3))) void*)((char*)BsBuf + (BUF) * 16384 + ldsoff),  \
                16, 0, 0);                                                                         \
        }

        FSTAGE(0, 0);
        for (int kt = 0; kt < KT; ++kt) {
            int cur = kt & 1;
            if (kt + 1 < KT) {
                FSTAGE(kt + 1, cur ^ 1);
                asm volatile("s_waitcnt vmcnt(2)" ::: "memory");
            } else {
                asm volatile("s_waitcnt vmcnt(0)" ::: "memory");
            }
            asm volatile("s_barrier" ::: "memory");
            bf16x8 af[4], bf[4];
#pragma unroll
            for (int f4 = 0; f4 < 4; ++f4) {
                af[f4] = *(const bf16x8*)((const char*)AsBuf + cur * 16384 + ((wr * 4 + f4) * 64 + lane) * 16);
                bf[f4] = *(const bf16x8*)((const char*)BsBuf + cur * 16384 + ((wc * 4 + f4) * 64 + lane) * 16);
            }
#pragma unroll
            for (int i = 0; i < 4; ++i)
#pragma unroll
                for (int j = 0; j < 4; ++j)
                    acc[i][j] = __builtin_amdgcn_mfma_f32_16x16x32_bf16(af[i], bf[j], acc[i][j], 0, 0, 0);
            asm volatile("s_barrier" ::: "memory");
        }
#undef FSTAGE

#pragma unroll
        for (int i = 0; i < 4; ++i) {
            int r0 = (int)bm + wr * 64 + i * 16 + (lane >> 4) * 4;
#pragma unroll
            for (int j = 0; j < 4; ++j) {
                int col = (int)bn + wc * 64 + j * 16 + (lane & 15);
                if (col < Nn) {
#pragma unroll
                    for (int e = 0; e < 4; ++e) {
                        int r = r0 + e;
                        if (r < N_BOX) C[(size_t)r * LDZ + col] = acc[i][j][e];
                    }
                }
            }
        }
        return;
    }
    int rb = b - 1 - NG;
    const int cq[9] = {0, 1, 2, 3, 1028, 1029, 1030, 1031, 1032};
    if (rb < 5) {
        int r = rb * 1024 + tid;
        if (r < 5120) {
            float* dst = E9 + (size_t)r * 12;
#pragma unroll
            for (int q = 0; q < 9; ++q) dst[q] = (r < N_BOX) ? X0[(size_t)r * LDX + cq[q]] : 0.0f;
            dst[9] = dst[10] = dst[11] = 0.0f;
        }
        return;
    }
    rb -= 5;
    if (rb < 2) {
        int n = rb * 1024 + tid;
        if (n < 2048) {
            float* dst = W9 + (size_t)n * 12;
            const float* src = (n < 1000) ? (Wg0full + (size_t)n * 1033)
                             : (n < 2000) ? (Wl0full + (size_t)(n - 1000) * 1033) : nullptr;
#pragma unroll
            for (int q = 0; q < 9; ++q) dst[q] = src ? src[cq[q]] : 0.0f;
            dst[9] = dst[10] = dst[11] = 0.0f;
        }
        return;
    }
    rb -= 2;
    int rowl = tid >> 8;
    int tid2 = tid & 255;
    if (rb < 320) {
        int n = rb * 4 + rowl;
        if (n < 1280) wconv_row(Wg1, Wl1, B2_1, n, tid2, 600, 1000, 1024);
        return;
    }
    rb -= 320;
    if (rb < 160) {
        int n = rb * 4 + rowl;
        if (n < 640) wconv_row(Wg2, Wl2, B2_2, n, tid2, 300, 600, 608);
        return;
    }
    rb -= 160;
    {
        int n = rb * 4 + rowl;
        if (n < 384) wconv_row(Wg3, Wl3, B2_3, n, tid2, 150, 300, 320);
        return;
    }
}

// ---------------- z9 patch + assign fused ----------------
__global__ void z9_assign_kernel(float* __restrict__ Z, const float* __restrict__ E9,
                                 const float* __restrict__ W9, int Nn,
                                 const unsigned long long* __restrict__ mask,
                                 const unsigned long long* __restrict__ keep,
                                 int* __restrict__ assign, int* __restrict__ counts) {
    int b = blockIdx.x;
    if (b < N_BOX) {
        int r = b;
        float e[9];
#pragma unroll
        for (int q = 0; q < 9; ++q) e[q] = E9[(size_t)r * 12 + q];
        for (int o = threadIdx.x; o < Nn; o += blockDim.x) {
            const float* w = W9 + (size_t)o * 12;
            float s = 0.0f;
#pragma unroll
            for (int q = 0; q < 9; ++q) s += e[q] * w[q];
            Z[(size_t)r * LDZ + o] += s;
        }
        return;
    }
    int i = (b - N_BOX) * 256 + threadIdx.x;
    if (i >= N_BOX) return;
    for (int w = 0; w < NCHUNK; ++w) {
        unsigned long long m = mask[(size_t)i * NW + w] & keep[w];
        if (m) {
            int j = w * 64 + __builtin_ctzll(m);
            assign[i] = j;
            atomicAdd(&counts[j], 1);
            return;
        }
    }
}

// ---------------- assign (fallback) ----------------
__global__ void assign_kernel(const unsigned long long* __restrict__ mask,
                              const unsigned long long* __restrict__ keep,
                              int* __restrict__ assign, int* __restrict__ counts) {
    int i = blockIdx.x * blockDim.x + threadIdx.x;
    if (i >= N_BOX) return;
    for (int w = 0; w < NCHUNK; ++w) {
        unsigned long long m = mask[(size_t)i * NW + w] & keep[w];
        if (m) {
            int j = w * 64 + __builtin_ctzll(m);
            assign[i] = j;
            atomicAdd(&counts[j], 1);
            return;
        }
    }
}

// ---------------- exclusive scan ----------------
__global__ __launch_bounds__(1024) void scan_kernel(const int* __restrict__ counts, int* __restrict__ offs) {
    __shared__ int part[1024];
    int t = threadIdx.x;
    int base = t * 5;
    int c[5];
    int s = 0;
#pragma unroll
    for (int k = 0; k < 5; ++k) {
        int idx = base + k;
        c[k] = (idx < N_BOX) ? counts[idx] : 0;
        s += c[k];
    }
    part[t] = s;
    __syncthreads();
    for (int d = 1; d < 1024; d <<= 1) {
        int v = part[t];
        int u = (t >= d) ? part[t - d] : 0;
        __syncthreads();
        part[t] = v + u;
        __syncthreads();
    }
    int run = (t > 0) ? part[t - 1] : 0;
#pragma unroll
    for (int k = 0; k < 5; ++k) {
        int idx = base + k;
        if (idx < N_BOX) offs[idx] = run;
        run += c[k];
    }
}

// ---------------- deterministic member scatter ----------------
__global__ void rankscatter_kernel(const int* __restrict__ assign, const int* __restrict__ offs,
                                   int* __restrict__ members) {
    __shared__ int a[N_BOX];
    int tid = threadIdx.x;
    for (int t = tid; t < N_BOX; t += blockDim.x) a[t] = assign[t];
    __syncthreads();
    int i = blockIdx.x * blockDim.x + tid;
    if (i >= N_BOX) return;
    int ai = a[i];
    int r = 0;
    for (int k = 0; k < i; ++k) r += (a[k] == ai);
    members[offs[ai] + r] = i;
}

// ---------------- wconv standalone, 2-term (L0) ----------------
__global__ void wconv_kernel(const float* __restrict__ Wg, const float* __restrict__ Wl,
                             unsigned short* __restrict__ B2, int dout, int din_src,
                             int din_eff, int colOff, int K16eff) {
    int n = blockIdx.x;
    unsigned short* dst = B2 + (size_t)n * LDAB;
    int K2 = 2 * K16eff;
    if (n >= 2 * dout) {
        for (int k = threadIdx.x; k < K2; k += blockDim.x) dst[k] = 0;
        return;
    }
    const float* src = (n < dout) ? (Wg + (size_t)n * din_src) : (Wl + (size_t)(n - dout) * din_src);
    for (int k = threadIdx.x; k < K2; k += blockDim.x) {
        int ks = (k >= K16eff) ? (k - K16eff) : k;
        float x = (ks < din_eff) ? src[colOff + ks] : 0.0f;
        dst[k] = f2bf(x);
    }
}

// ---------------- MFMA bf16 GEMM, 128x128, BK=32, dbuf, 4 blk/CU (L1..L3) ----------------
__global__ __launch_bounds__(256, 4) void gemm_mfma(const unsigned short* __restrict__ A2,
                                                    const unsigned short* __restrict__ B2,
                                                    float* __restrict__ C, int KT, int Nn) {
    __shared__ unsigned short AsBuf[2 * 4096];
    __shared__ unsigned short BsBuf[2 * 4096];
    int tid = threadIdx.x;
    int lane = tid & 63;
    int wave = tid >> 6;
    int wr = wave >> 1, wc = wave & 1;
    size_t bm = (size_t)blockIdx.x * 128;
    size_t bn = (size_t)blockIdx.y * 128;

    f32x4v acc[4][4];
#pragma unroll
    for (int i = 0; i < 4; ++i)
#pragma unroll
        for (int j = 0; j < 4; ++j) acc[i][j] = (f32x4v){0.f, 0.f, 0.f, 0.f};

    const unsigned short* gA[2];
    const unsigned short* gB[2];
    unsigned ldsoff[2];
#pragma unroll
    for (int q = 0; q < 2; ++q) {
        int f = q * 4 + wave;
        int grow = f * 16 + (lane & 15);
        int gcol = (lane >> 4) * 8;
        gA[q] = A2 + (bm + grow) * (size_t)LDAB + gcol;
        gB[q] = B2 + (bn + grow) * (size_t)LDAB + gcol;
        ldsoff[q] = (unsigned)((f * 64 + lane) * 16);
    }

#define STAGE(T, BUF)                                                                              \
    {                                                                                              \
        size_t ko = (size_t)(T) * 32;                                                              \
        _Pragma("unroll") for (int q = 0; q < 2; ++q) {                                            \
            __builtin_amdgcn_global_load_lds(                                                      \
                (const __attribute__((address_space(1))) void*)(gA[q] + ko),                       \
                (__attribute__((address_space(3))) void*)((char*)AsBuf + (BUF) * 8192 + ldsoff[q]),\
                16, 0, 0);                                                                         \
            __builtin_amdgcn_global_load_lds(                                                      \
                (const __attribute__((address_space(1))) void*)(gB[q] + ko),                       \
                (__attribute__((address_space(3))) void*)((char*)BsBuf + (BUF) * 8192 + ldsoff[q]),\
                16, 0, 0);                                                                         \
        }                                                                                          \
    }

    STAGE(0, 0);
    for (int kt = 0; kt < KT; ++kt) {
        int cur = kt & 1;
        if (kt + 1 < KT) {
            STAGE(kt + 1, cur ^ 1);
            asm volatile("s_waitcnt vmcnt(4)" ::: "memory");
        } else {
            asm volatile("s_waitcnt vmcnt(0)" ::: "memory");
        }
        asm volatile("s_barrier" ::: "memory");
        bf16x8 af[4], bf[4];
#pragma unroll
        for (int f4 = 0; f4 < 4; ++f4) {
            af[f4] = *(const bf16x8*)((const char*)AsBuf + cur * 8192 + ((wr * 4 + f4) * 64 + lane) * 16);
            bf[f4] = *(const bf16x8*)((const char*)BsBuf + cur * 8192 + ((wc * 4 + f4) * 64 + lane) * 16);
        }
#pragma unroll
        for (int i = 0; i < 4; ++i)
#pragma unroll
            for (int j = 0; j < 4; ++j)
                acc[i][j] = __builtin_amdgcn_mfma_f32_16x16x32_bf16(af[i], bf[j], acc[i][j], 0, 0, 0);
        asm volatile("s_barrier" ::: "memory");
    }
#undef STAGE

#pragma unroll
    for (int i = 0; i < 4; ++i) {
        int r0 = (int)bm + wr * 64 + i * 16 + (lane >> 4) * 4;
#pragma unroll
        for (int j = 0; j < 4; ++j) {
            int col = (int)bn + wc * 64 + j * 16 + (lane & 15);
            if (col < Nn) {
#pragma unroll
                for (int e = 0; e < 4; ++e) {
                    int r = r0 + e;
                    if (r < N_BOX) C[(size_t)r * LDZ + col] = acc[i][j][e];
                }
            }
        }
    }
}

// ---------------- f32 fallback pack ----------------
__global__ void wcat_kernel(const float* __restrict__ Wg, const float* __restrict__ Wl,
                            float* __restrict__ Wc, int dout, int din, int K16) {
    int row = blockIdx.x;
    const float* src = (row < dout) ? (Wg + (size_t)row * din) : (Wl + (size_t)(row - dout) * din);
    float* dst = Wc + (size_t)row * LDW;
    for (int k = threadIdx.x; k < K16; k += blockDim.x)
        dst[k] = (k < din) ? src[k] : 0.0f;
}

// ---------------- f32 GEMM (fallback) ----------------
__global__ __launch_bounds__(256) void gemm_nt(const float* __restrict__ A, const float* __restrict__ B,
                                               float* __restrict__ C, int M, int Nn, int K16) {
    __shared__ float As[16][64];
    __shared__ float Bs[16][64];
    int bm = blockIdx.x * 64;
    int bn = blockIdx.y * 64;
    int tid = threadIdx.x;
    int row = tid & 63;
    int kq  = tid >> 6;
    int tx  = tid & 15;
    int ty  = tid >> 4;
    float acc[4][4] = {};
    for (int k0 = 0; k0 < K16; k0 += 16) {
        float4 av = make_float4(0.f, 0.f, 0.f, 0.f);
        float4 bv = make_float4(0.f, 0.f, 0.f, 0.f);
        if (bm + row < M)  av = *(const float4*)&A[(size_t)(bm + row) * LDX + k0 + kq * 4];
        if (bn + row < Nn) bv = *(const float4*)&B[(size_t)(bn + row) * LDW + k0 + kq * 4];
        __syncthreads();
        As[kq * 4 + 0][row] = av.x; As[kq * 4 + 1][row] = av.y;
        As[kq * 4 + 2][row] = av.z; As[kq * 4 + 3][row] = av.w;
        Bs[kq * 4 + 0][row] = bv.x; Bs[kq * 4 + 1][row] = bv.y;
        Bs[kq * 4 + 2][row] = bv.z; Bs[kq * 4 + 3][row] = bv.w;
        __syncthreads();
#pragma unroll
        for (int kk = 0; kk < 16; ++kk) {
            float4 a = *(const float4*)&As[kk][ty * 4];
            float4 b = *(const float4*)&Bs[kk][tx * 4];
            float aa[4] = {a.x, a.y, a.z, a.w};
            float bb[4] = {b.x, b.y, b.z, b.w};
#pragma unroll
            for (int i = 0; i < 4; ++i)
#pragma unroll
                for (int jx = 0; jx < 4; ++jx) acc[i][jx] += aa[i] * bb[jx];
        }
    }
#pragma unroll
    for (int i = 0; i < 4; ++i) {
        int r = bm + ty * 4 + i;
        if (r >= M) break;
#pragma unroll
        for (int jx = 0; jx < 4; ++jx) {
            int ccol = bn + tx * 4 + jx;
            if (ccol < Nn) C[(size_t)r * LDZ + ccol] = acc[i][jx];
        }
    }
}

// ---------------- segment mean of Zl ----------------
__global__ void segmean_kernel(const float* __restrict__ Z, int dout,
                               const int* __restrict__ counts, const int* __restrict__ offs,
                               const int* __restrict__ members, float* __restrict__ ym) {
    int j = blockIdx.x;
    int cnt = counts[j];
    if (cnt == 0) return;
    int off = offs[j];
    float fc = (float)cnt;
    for (int o = threadIdx.x; o < dout; o += blockDim.x) {
        float s = 0.0f;
        for (int m = 0; m < cnt; ++m) {
            int i = members[off + m];
            s += Z[(size_t)i * LDZ + dout + o];
        }
        ym[(size_t)j * LDYM + o] = s / fc;
    }
}

// ---------------- combine + ELU -> f32 X (L3 + fallback) ----------------
__global__ void combine_kernel(const float* __restrict__ Z, const float* __restrict__ bg,
                               const float* __restrict__ ym, const int* __restrict__ assign,
                               float* __restrict__ Xout, int dout, int doutPad) {
    int r = blockIdx.x;
    int a = assign[r];
    float* dst = Xout + (size_t)r * LDX;
    for (int o = threadIdx.x; o < doutPad; o += blockDim.x) {
        float v = 0.0f;
        if (o < dout) {
            float z = Z[(size_t)r * LDZ + o] + bg[o] - ym[(size_t)a * LDYM + o];
            v = (z > 0.0f) ? z : expm1f(z);
        }
        dst[o] = v;
    }
}

// ---------------- combine + ELU -> bf16 A2 SINGLE-term (L0..L2) ----------------
__global__ void combine_fused_kernel(const float* __restrict__ Z, const float* __restrict__ bg,
                                     const float* __restrict__ ym, const int* __restrict__ assign,
                                     unsigned short* __restrict__ A2, int dout, int K16next) {
    int r = blockIdx.x;
    int a = assign[r];
    unsigned short* dst = A2 + (size_t)r * LDAB;
    for (int o = threadIdx.x; o < K16next; o += blockDim.x) {
        float v = 0.0f;
        if (o < dout) {
            float z = Z[(size_t)r * LDZ + o] + bg[o] - ym[(size_t)a * LDYM + o];
            v = (z > 0.0f) ? z : expm1f(z);
        }
        dst[o] = f2bf(v);
    }
}

// ---------------- L4 mini-path ----------------
__global__ void l4a_kernel(const float* __restrict__ X, const float* __restrict__ Wg,
                           const float* __restrict__ Wl, float* __restrict__ zg,
                           float* __restrict__ zl) {
    int r = blockIdx.x * blockDim.x + threadIdx.x;
    if (r >= N_BOX) return;
    const float* row = X + (size_t)r * LDX;
    float sg = 0.0f, sl = 0.0f;
    for (int k = 0; k < 150; ++k) {
        float x = row[k];
        sg += x * Wg[k];
        sl += x * Wl[k];
    }
    zg[r] = sg;
    zl[r] = sl;
}

__global__ __launch_bounds__(64) void l4b_kernel(const float* __restrict__ zl,
                                                 const int* __restrict__ counts,
                                                 const int* __restrict__ offs,
                                                 const int* __restrict__ members,
                                                 float* __restrict__ ym4) {
    int j = blockIdx.x;
    int cnt = counts[j];
    if (cnt == 0) return;
    int off = offs[j];
    int l = threadIdx.x;
    float s = 0.0f;
    for (int m = l; m < cnt; m += 64) s += zl[members[off + m]];
#pragma unroll
    for (int d = 1; d < 64; d <<= 1) s += __shfl_xor(s, d);
    if (l == 0) ym4[j] = s / (float)cnt;
}

__global__ void l4c_kernel(const float* __restrict__ zg, const float* __restrict__ ym4,
                           const float* __restrict__ bg, const int* __restrict__ assign,
                           const int* __restrict__ counts, float* __restrict__ out) {
    int r = blockIdx.x * blockDim.x + threadIdx.x;
    if (r >= N_BOX) return;
    int a = assign[r];
    float z = zg[r] + bg[0] - ym4[a];
    float v = (z > 0.0f) ? z : expm1f(z);
    out[r] = (counts[a] >= 2) ? v : 0.0f;
}

// ---------------- final mask (fallback) ----------------
__global__ void final_kernel(const float* __restrict__ X, const int* __restrict__ assign,
                             const int* __restrict__ counts, float* __restrict__ out) {
    int r = blockIdx.x * blockDim.x + threadIdx.x;
    if (r >= N_BOX) return;
    out[r] = (counts[assign[r]] >= 2) ? X[(size_t)r * LDX] : 0.0f;
}

extern "C" void kernel_launch(void* const* d_in, const int* in_sizes, int n_in,
                              void* d_out, int out_size, void* d_ws, size_t ws_size,
                              hipStream_t stream) {
    const float* bb    = (const float*)d_in[0];
    const float* cls   = (const float*)d_in[1];
    const float* feats = (const float*)d_in[2];
    const float* img   = (const float*)d_in[3];

    char* ws = (char*)d_ws;
    size_t off = 0;
    auto alloc = [&](size_t bytes) -> void* {
        void* p = ws + off;
        off += (bytes + 255) & ~(size_t)255;
        return p;
    };
    int*   ord     = (int*)alloc((size_t)N_BOX * 4);
    int*   rankb   = (int*)alloc((size_t)N_BOX * 4);
    float* sb      = (float*)alloc((size_t)6 * N_BOX * 4);
    int*   assign  = (int*)alloc((size_t)N_BOX * 4);
    int*   counts  = (int*)alloc((size_t)N_BOX * 4);
    int*   offsb   = (int*)alloc((size_t)N_BOX * 4);
    int*   members = (int*)alloc((size_t)N_BOX * 4);
    unsigned long long* mask = (unsigned long long*)alloc((size_t)(NCHUNK * 64) * NW * 8);
    unsigned long long* diag = (unsigned long long*)alloc((size_t)NCHUNK * 64 * 8);
    unsigned long long* keep = (unsigned long long*)alloc((size_t)NCHUNK * 8 + 1024);
    float* Xa = (float*)alloc((size_t)N_BOX * LDX * 4);
    float* Xb = (float*)alloc((size_t)N_BOX * LDX * 4);
    float* Z  = (float*)alloc((size_t)N_BOX * LDZ * 4);
    float* ym = (float*)alloc((size_t)N_BOX * LDYM * 4);
    float* Wc = (float*)alloc((size_t)2000 * LDW * 4);
    unsigned short* A2   = (unsigned short*)alloc((size_t)5120 * LDAB * 2);
    unsigned short* B2_0 = (unsigned short*)alloc((size_t)2048 * LDAB * 2);
    unsigned short* B2_1 = (unsigned short*)alloc((size_t)1280 * LDAB * 2);
    unsigned short* B2_2 = (unsigned short*)alloc((size_t)640 * LDAB * 2);
    unsigned short* B2_3 = (unsigned short*)alloc((size_t)384 * LDAB * 2);
    float* E9 = (float*)alloc((size_t)5120 * 12 * 4);
    float* W9 = (float*)alloc((size_t)2048 * 12 * 4);
    float* zg  = (float*)alloc((size_t)N_BOX * 4);
    float* zl  = (float*)alloc((size_t)N_BOX * 4);
    float* ym4 = (float*)alloc((size_t)N_BOX * 4);
    bool use_mfma = (off <= ws_size);

    hipMemsetAsync(rankb, 0, (size_t)N_BOX * 4, stream);
    rank_partial_kernel<<<dim3(RT, RT), dim3(256), 0, stream>>>(cls, rankb);
    rank_scatter_kernel<<<dim3(RT), dim3(256), 0, stream>>>(rankb, ord);
    gather_kernel<<<dim3(5120), dim3(256), 0, stream>>>(bb, cls, feats, img, ord, Xa, sb, A2);
    mask_kernel<<<dim3(N_BOX), dim3(256), 0, stream>>>(sb, mask, diag, counts);

    const int dins[5]  = {1033, 1000, 600, 300, 150};
    const int douts[5] = {1000, 600, 300, 150, 1};
    const int K16s[4]  = {1024, 1024, 608, 320};   // L0: per-half (2-term); L1-3: single-term
    const int KTs[4]   = {64, 32, 19, 10};
    unsigned short* B2L[4] = {B2_0, B2_1, B2_2, B2_3};

    if (use_mfma) {
        wconv_kernel<<<dim3(2048), dim3(256), 0, stream>>>((const float*)d_in[4], (const float*)d_in[6],
                                                           B2_0, 1000, 1033, 1024, 4, 1024);
        nms_gemm_fused<<<dim3(744), dim3(1024), 0, stream>>>(
            mask, diag, keep, A2, B2_0, Z, KTs[0], 2000, 20,
            Xa, E9, W9,
            (const float*)d_in[7], (const float*)d_in[9],
            (const float*)d_in[4], (const float*)d_in[6],
            B2_1,
            (const float*)d_in[10], (const float*)d_in[12], B2_2,
            (const float*)d_in[13], (const float*)d_in[15], B2_3);
        z9_assign_kernel<<<dim3(N_BOX + RT), dim3(256), 0, stream>>>(Z, E9, W9, 2000,
                                                                     mask, keep, assign, counts);
        scan_kernel<<<dim3(1), dim3(1024), 0, stream>>>(counts, offsb);
        rankscatter_kernel<<<dim3(RT), dim3(256), 0, stream>>>(assign, offsb, members);

        for (int L = 0; L < 4; ++L) {
            const float* bg = (const float*)d_in[5 + 3 * L];
            int dout = douts[L];
            int N2 = 2 * dout;
            if (L > 0) {
                int Ntiles = (N2 + 127) >> 7;
                gemm_mfma<<<dim3(40, Ntiles), dim3(256), 0, stream>>>(A2, B2L[L], Z, KTs[L], N2);
            }
            segmean_kernel<<<dim3(N_BOX), dim3(256), 0, stream>>>(Z, dout, counts, offsb, members, ym);
            if (L < 3) {
                combine_fused_kernel<<<dim3(N_BOX), dim3(256), 0, stream>>>(Z, bg, ym, assign, A2,
                                                                            dout, K16s[L + 1]);
            } else {
                combine_kernel<<<dim3(N_BOX), dim3(256), 0, stream>>>(Z, bg, ym, assign, Xa, dout, 160);
            }
        }
        l4a_kernel<<<dim3(RT), dim3(256), 0, stream>>>(Xa, (const float*)d_in[16],
                                                       (const float*)d_in[18], zg, zl);
        l4b_kernel<<<dim3(N_BOX), dim3(64), 0, stream>>>(zl, counts, offsb, members, ym4);
        l4c_kernel<<<dim3(RT), dim3(256), 0, stream>>>(zg, ym4, (const float*)d_in[17],
                                                       assign, counts, (float*)d_out);
    } else {
        nms_scan_kernel<<<dim3(1), dim3(1024), 0, stream>>>(mask, diag, keep);
        assign_kernel<<<dim3(RT), dim3(256), 0, stream>>>(mask, keep, assign, counts);
        scan_kernel<<<dim3(1), dim3(1024), 0, stream>>>(counts, offsb);
        rankscatter_kernel<<<dim3(RT), dim3(256), 0, stream>>>(assign, offsb, members);
        for (int L = 0; L < 5; ++L) {
            const float* Wg = (const float*)d_in[4 + 3 * L];
            const float* bg = (const float*)d_in[5 + 3 * L];
            const float* Wl = (const float*)d_in[6 + 3 * L];
            int din = dins[L], dout = douts[L];
            int K16 = (din + 15) & ~15;
            int N2 = 2 * dout;
            int doutPad = (dout + 15) & ~15;
            float* Xin  = (L % 2 == 0) ? Xa : Xb;
            float* Xout = (L % 2 == 0) ? Xb : Xa;
            wcat_kernel<<<dim3(N2), dim3(256), 0, stream>>>(Wg, Wl, Wc, dout, din, K16);
            gemm_nt<<<dim3((N_BOX + 63) / 64, (N2 + 63) / 64), dim3(256), 0, stream>>>(Xin, Wc, Z, N_BOX, N2, K16);
            segmean_kernel<<<dim3(N_BOX), dim3(256), 0, stream>>>(Z, dout, counts, offsb, members, ym);
            combine_kernel<<<dim3(N_BOX), dim3(256), 0, stream>>>(Z, bg, ym, assign, Xout, dout, doutPad);
        }
        final_kernel<<<dim3(RT), dim3(256), 0, stream>>>(Xb, assign, counts, (float*)d_out);
    }
}